// Round 7
// baseline (28.751 us; speedup 1.0000x reference)
//
#include <hip/hip_runtime.h>

// FK over the SMPL joint tree — joint-per-lane, pointer-doubling shuffles.
// Lane layout: lanes [0,32) handle frame A, [32,64) frame B; within a group,
// lane j < 22 owns joint j (lanes 22-31 idle; no memory ops from them).
// Each lane: load its joint's 6 floats (24B contiguous, wave covers 2 whole
// frames), Gram-Schmidt -> local R, then 3 pointer-doubling steps
//   A[j] = A[anc_s[j]] @ A[j]   (anc tables = parent, parent^2, parent^4 —
// compile-time constants packed into u64 immediates; active masks are the
// compares j>=1 / j>=4 / j>=10 since depth is monotone in joint id),
// then store rows 0..1 (6 floats). No LDS, no barriers — occupancy is
// VGPR-bound only, and loads/stores are independent per wave (deep MLP).

#define TPB 256  // 4 waves = 8 frames per block

namespace {
constexpr int PAR1[22] = {0,0,0,0,1,2,3,4,5,6,7,8,9,9,9,12,13,14,16,17,18,19};
constexpr int PAR2[22] = {0,0,0,0,0,0,0,1,2,3,4,5,6,6,6,9,9,9,13,14,16,17};   // par^2 (valid j>=4)
constexpr int PAR4[22] = {0,0,0,0,0,0,0,0,0,0,0,0,0,0,0,3,3,3,6,6,9,9};       // par^4 (valid j>=10)

__device__ __host__ constexpr unsigned long long pack5(const int (&t)[22], int base) {
    unsigned long long v = 0;
    for (int i = 0; i < 11; ++i)
        v |= (unsigned long long)(t[base + i] & 31) << (5 * i);
    return v;
}
constexpr unsigned long long P1L = pack5(PAR1, 0), P1H = pack5(PAR1, 11);
constexpr unsigned long long P2L = pack5(PAR2, 0), P2H = pack5(PAR2, 11);
constexpr unsigned long long P4L = pack5(PAR4, 0), P4H = pack5(PAR4, 11);
}  // namespace

__device__ __forceinline__ void mm3(float* __restrict__ D, const float* __restrict__ P,
                                    const float* __restrict__ L) {
#pragma unroll
    for (int r = 0; r < 3; ++r)
#pragma unroll
        for (int c = 0; c < 3; ++c)
            D[3 * r + c] = P[3 * r + 0] * L[0 + c] +
                           P[3 * r + 1] * L[3 + c] +
                           P[3 * r + 2] * L[6 + c];
}

__global__ __launch_bounds__(TPB) void fk6d_kernel(const float* __restrict__ in,
                                                   float* __restrict__ out, int N)
{
    const int tid = threadIdx.x;
    const int lane = tid & 63;
    const int base = lane & 32;           // shuffle-group base (frame A/B)
    const int j = lane & 31;              // joint id within group (valid < 22)
    const int frame = blockIdx.x * 8 + ((tid >> 6) << 1) + (lane >> 5);
    const bool act = (j < 22) && (frame < N);
    const int jc = (j < 22) ? j : 21;     // clamped for table shifts (amt <= 50)
    const int jm = (jc < 11) ? jc : jc - 11;
    const int sh = 5 * jm;

    const int a1 = (int)(((jc < 11) ? P1L : P1H) >> sh) & 31;
    const int a2 = (int)(((jc < 11) ? P2L : P2H) >> sh) & 31;
    const int a4 = (int)(((jc < 11) ? P4L : P4H) >> sh) & 31;

    // ---- load 6 floats + Gram-Schmidt -> A = local rotation (row-major)
    float A[9];
    if (act) {
        const float* s = in + (size_t)frame * 132 + j * 6;
        float2 d0 = *reinterpret_cast<const float2*>(s);
        float2 d1 = *reinterpret_cast<const float2*>(s + 2);
        float2 d2 = *reinterpret_cast<const float2*>(s + 4);
        float a1x = d0.x, a1y = d0.y, a1z = d1.x;
        float a2x = d1.y, a2y = d2.x, a2z = d2.y;
        float n1 = sqrtf(a1x * a1x + a1y * a1y + a1z * a1z);
        float i1 = 1.0f / fmaxf(n1, 1e-12f);
        float b1x = a1x * i1, b1y = a1y * i1, b1z = a1z * i1;
        float dt = b1x * a2x + b1y * a2y + b1z * a2z;
        float cx = a2x - dt * b1x, cy = a2y - dt * b1y, cz = a2z - dt * b1z;
        float n2 = sqrtf(cx * cx + cy * cy + cz * cz);
        float i2 = 1.0f / fmaxf(n2, 1e-12f);
        A[0] = b1x; A[1] = b1y; A[2] = b1z;
        A[3] = cx * i2; A[4] = cy * i2; A[5] = cz * i2;
        A[6] = A[1] * A[5] - A[2] * A[4];
        A[7] = A[2] * A[3] - A[0] * A[5];
        A[8] = A[0] * A[4] - A[1] * A[3];
    } else {
#pragma unroll
        for (int k = 0; k < 9; ++k) A[k] = 0.0f;
    }

    // ---- pointer-doubling: after step s, A = product of up to 2^s locals
    // step 1: segments of 2 (active depth>=1 <=> j>=1)
    {
        float M[9], T[9];
        int src = base | a1;
#pragma unroll
        for (int k = 0; k < 9; ++k) M[k] = __shfl(A[k], src, 64);
        mm3(T, M, A);
        bool on = (j >= 1);
#pragma unroll
        for (int k = 0; k < 9; ++k) A[k] = on ? T[k] : A[k];
    }
    // step 2: segments of 4 (active depth>=2 <=> j>=4)
    {
        float M[9], T[9];
        int src = base | a2;
#pragma unroll
        for (int k = 0; k < 9; ++k) M[k] = __shfl(A[k], src, 64);
        mm3(T, M, A);
        bool on = (j >= 4);
#pragma unroll
        for (int k = 0; k < 9; ++k) A[k] = on ? T[k] : A[k];
    }
    // step 3: segments of 8 (active depth>=4 <=> j>=10; max depth 7)
    {
        float M[9], T[9];
        int src = base | a4;
#pragma unroll
        for (int k = 0; k < 9; ++k) M[k] = __shfl(A[k], src, 64);
        mm3(T, M, A);
        bool on = (j >= 10);
#pragma unroll
        for (int k = 0; k < 9; ++k) A[k] = on ? T[k] : A[k];
    }

    // ---- store rows 0..1 of the global rotation
    if (act) {
        float* d = out + (size_t)frame * 132 + j * 6;
        *reinterpret_cast<float2*>(d)     = make_float2(A[0], A[1]);
        *reinterpret_cast<float2*>(d + 2) = make_float2(A[2], A[3]);
        *reinterpret_cast<float2*>(d + 4) = make_float2(A[4], A[5]);
    }
}

extern "C" void kernel_launch(void* const* d_in, const int* in_sizes, int n_in,
                              void* d_out, int out_size, void* d_ws, size_t ws_size,
                              hipStream_t stream) {
    const float* in = (const float*)d_in[0];
    float* out = (float*)d_out;
    int N = in_sizes[0] / 132;            // 100352 frames
    int grid = (N + 7) / 8;               // 8 frames per 256-thread block
    fk6d_kernel<<<grid, TPB, 0, stream>>>(in, out, N);
}